// Round 1
// 492.420 us; speedup vs baseline: 1.0880x; 1.0880x over previous
//
#include <hip/hip_runtime.h>
#include <stdint.h>

#define LBL 50
#define NL 52
#define L2E 1.4426950408889634f
#define BB 128
#define SS 512
#define DD 1024

typedef __attribute__((ext_vector_type(8))) short short8;
typedef __attribute__((ext_vector_type(4))) float float4v;
typedef __attribute__((ext_vector_type(2))) float float2v;

union S8U { unsigned int u[4]; short8 s; };

static __device__ __forceinline__ unsigned int f2bf(float f) {
    union { float f; unsigned int u; } v; v.f = f;
    unsigned int r = v.u + 0x7fffu + ((v.u >> 16) & 1u);
    return r >> 16;
}

// ---------------------------------------------------------------------------
// Kernel 0: W [50,1024] f32 -> Wbf [64,1024] bf16 (rows 50..63 zero), rounded.
// ---------------------------------------------------------------------------
__global__ __launch_bounds__(256) void wconv(
    const float* __restrict__ W, unsigned short* __restrict__ Wbf)
{
    int i = blockIdx.x * 256 + threadIdx.x;   // 0..65535
    int r = i >> 10, c = i & 1023;
    float v = (r < LBL) ? W[r * DD + c] : 0.f;
    Wbf[i] = (unsigned short)f2bf(v);
}

// ---------------------------------------------------------------------------
// Kernel 1: PEp[r, c] = exp(sum_d A[r,d]*W[c,d] + b[c]) for c<50, else 0.
// Padded [r][64] output. LDS-free: A-frags straight from global (trunc-pack
// via v_perm), B-frags from pre-converted Wbf (L2-resident).
// ---------------------------------------------------------------------------
__global__ __launch_bounds__(256) void gemm_pe(
    const float* __restrict__ A,            // [65536,1024]
    const unsigned short* __restrict__ Wbf, // [64,1024] bf16
    const float* __restrict__ bias,         // [50]
    float* __restrict__ PEp)                // [65536,64]
{
    const int tid  = threadIdx.x;
    const int lane = tid & 63;
    const int wv   = tid >> 6;
    const int mrow = lane & 15;
    const int quad = lane >> 4;
    const int row  = blockIdx.x * 64 + wv * 16 + mrow;

    const uint4* arow = (const uint4*)(A + (size_t)row * DD);

    float4v acc[4];
#pragma unroll
    for (int i = 0; i < 4; ++i) acc[i] = (float4v){0.f, 0.f, 0.f, 0.f};

#pragma unroll 4
    for (int kc = 0; kc < DD; kc += 32) {
        uint4 u0 = arow[(kc >> 2) + quad * 2];
        uint4 u1 = arow[(kc >> 2) + quad * 2 + 1];
        S8U a;
        a.u[0] = __builtin_amdgcn_perm(u0.y, u0.x, 0x07060302u);
        a.u[1] = __builtin_amdgcn_perm(u0.w, u0.z, 0x07060302u);
        a.u[2] = __builtin_amdgcn_perm(u1.y, u1.x, 0x07060302u);
        a.u[3] = __builtin_amdgcn_perm(u1.w, u1.z, 0x07060302u);
#pragma unroll
        for (int nt = 0; nt < 4; ++nt) {
            short8 bf = *(const short8*)(Wbf + (size_t)(nt * 16 + mrow) * DD + kc + quad * 8);
            acc[nt] = __builtin_amdgcn_mfma_f32_16x16x32_bf16(a.s, bf, acc[nt], 0, 0, 0);
        }
    }
    // epilogue: C[row=quad*4+r][col=nt*16+mrow]
    const int r0 = blockIdx.x * 64 + wv * 16 + quad * 4;
#pragma unroll
    for (int nt = 0; nt < 4; ++nt) {
        int col = nt * 16 + mrow;
        float bv = (col < LBL) ? bias[col] : 0.f;
#pragma unroll
        for (int rr = 0; rr < 4; ++rr) {
            float val = (col < LBL) ? __builtin_amdgcn_exp2f((acc[nt][rr] + bv) * L2E) : 0.f;
            PEp[(size_t)(r0 + rr) * 64 + col] = val;
        }
    }
}

// ---------------------------------------------------------------------------
// Kernel 2: MFMA-batched CRF forward, 8 blocks x 16 chains.
//
// NEW: the constant A operand (exp(T)) is ROW-PERMUTED by
//   sigma(it*16+m) = (m>>2)*8 + (m&3) + 4*(it&1) + 32*(it>>1)
// so that the MFMA C-layout output acc[it][r] at lane (b,q) holds exactly the
// labels {q*8+r + 4*(it&1) + 32*(it>>1)} = this lane's NEXT-step B-fragment
// (k = q*8+reg, chunk jt = it>>1). The 16 ds_bpermute per step (the serial
// critical path's LDS round trip) are eliminated: C->B relayout is 8 lane-
// local v_perm packs. END label 51 now sits at acc[2][3] on q==2 lanes
// (forced: quad(51)=2); final reduce moved to q==2. Exponent broadcast still
// samples lane b (= quad0, label 0) -> scale sequence numerically identical.
// ---------------------------------------------------------------------------
__global__ __launch_bounds__(128) void crf_fwd(
    const float* __restrict__ PE,     // [65536,64] padded exp(logits)
    const float* __restrict__ T,      // [52,52]
    const int*   __restrict__ lens,   // [128]
    const int*   __restrict__ labels, // [128,512]
    float* __restrict__ out)          // [1], pre-zeroed
{
    const int g    = blockIdx.x;
    const int tid  = threadIdx.x;
    const int lane = tid & 63;
    const int wv   = tid >> 6;
    const int b    = lane & 15;
    const int q    = lane >> 4;

    __shared__ float gold_sh[16];
    float norm_e = 0.f;

    if (wv == 0) {
        const int bb   = g * 16 + b;
        const int lenl = lens[bb];

        // constant A-frags: sigma-permuted e^T rows; A[m=lane&15][k=q*8+reg]
        short8 afr[4][2];
#pragma unroll
        for (int it = 0; it < 4; ++it) {
            int i = (b >> 2) * 8 + (b & 3) + 4 * (it & 1) + 32 * (it >> 1);
#pragma unroll
            for (int jt = 0; jt < 2; ++jt) {
                S8U pk;
#pragma unroll
                for (int h = 0; h < 4; ++h) {
                    int k0 = jt * 32 + q * 8 + 2 * h;
                    float v0 = (i < NL && k0     < NL) ? __builtin_amdgcn_exp2f(T[i * NL + k0]     * L2E) : 0.f;
                    float v1 = (i < NL && k0 + 1 < NL) ? __builtin_amdgcn_exp2f(T[i * NL + k0 + 1] * L2E) : 0.f;
                    pk.u[h] = f2bf(v0) | (f2bf(v1) << 16);
                }
                afr[it][jt] = pk.s;
            }
        }

        const int addrB = b * 4;

        // per-lane PE base: labels [q*8, q*8+8) and [32+q*8, 32+q*8+8)
        // i.e. float4 indices q*2, q*2+1, 8+q*2, 8+q*2+1 of each 64-f row.
        const float4* lb = (const float4*)(PE + (size_t)bb * SS * 64 + q * 8);

#define LOADP4(dst, trow) do {                                           \
        const float4* _p = lb + (size_t)(trow) * 16;                     \
        float4 _a0 = _p[0], _a1 = _p[1], _a2 = _p[8], _a3 = _p[9];       \
        dst[0]=_a0.x;  dst[1]=_a0.y;  dst[2]=_a0.z;  dst[3]=_a0.w;       \
        dst[4]=_a1.x;  dst[5]=_a1.y;  dst[6]=_a1.z;  dst[7]=_a1.w;       \
        dst[8]=_a2.x;  dst[9]=_a2.y;  dst[10]=_a2.z; dst[11]=_a2.w;      \
        dst[12]=_a3.x; dst[13]=_a3.y; dst[14]=_a3.z; dst[15]=_a3.w;      \
    } while (0)

        // init E_1[slot] = PE[row0][sigma(slot)] * e^{T[sigma(slot)][START]}
        float E[16];
        {
            float p0[16];
            LOADP4(p0, 0);
#pragma unroll
            for (int k = 0; k < 16; ++k) {
                int it = k >> 2, r = k & 3;
                int i = q * 8 + r + 4 * (it & 1) + 32 * (it >> 1);
                float ets = (i < NL) ? __builtin_amdgcn_exp2f(T[i * NL + LBL] * L2E) : 0.f;
                E[k] = p0[k] * ets;
            }
        }

        float r0[16], r1[16], r2[16], r3[16];
        LOADP4(r0, 1); LOADP4(r1, 2); LOADP4(r2, 3); LOADP4(r3, 4);

        float ncap = 1.0f;
        int lcap = 0, lsum = 0, ebp = 127;

#define STEP(PC, t) do {                                                          \
        /* lane-local C->B repack: bfr[jt] = E slots [8jt .. 8jt+7] */            \
        S8U bfr[2];                                                               \
        _Pragma("unroll")                                                         \
        for (int jt = 0; jt < 2; ++jt) {                                          \
            _Pragma("unroll")                                                     \
            for (int u = 0; u < 4; ++u) {                                         \
                bfr[jt].u[u] = __builtin_amdgcn_perm(                             \
                    __float_as_uint(E[jt * 8 + 2 * u + 1]),                       \
                    __float_as_uint(E[jt * 8 + 2 * u]), 0x07060302u);             \
            }                                                                     \
        }                                                                         \
        const float4v zz = (float4v){0.f, 0.f, 0.f, 0.f};                         \
        float4v acc[4];                                                           \
        _Pragma("unroll")                                                         \
        for (int it = 0; it < 4; ++it) {                                          \
            float4v a0 = __builtin_amdgcn_mfma_f32_16x16x32_bf16(afr[it][0], bfr[0].s, zz, 0, 0, 0); \
            acc[it]    = __builtin_amdgcn_mfma_f32_16x16x32_bf16(afr[it][1], bfr[1].s, a0, 0, 0, 0); \
        }                                                                         \
        bool cap = ((t) == lenl);                                                 \
        ncap = cap ? acc[2][3] : ncap;  /* END=51 at it=2,r=3 on q==2 lanes */    \
        lcap = cap ? lsum : lcap;                                                 \
        float s = __uint_as_float((unsigned int)(254 - ebp) << 23);               \
        lsum += 127 - ebp;                                                        \
        int myeb = (int)((__float_as_uint(acc[0][0]) >> 23) & 0xffu);             \
        ebp = __builtin_amdgcn_ds_bpermute(addrB, myeb);                          \
        float2v s2 = (float2v){s, s};                                             \
        _Pragma("unroll")                                                         \
        for (int h = 0; h < 8; ++h) {                                             \
            float2v d2 = (float2v){acc[h>>1][(h&1)*2], acc[h>>1][(h&1)*2+1]};     \
            float2v p2 = (float2v){PC[2*h], PC[2*h+1]};                           \
            float2v e2 = d2 * p2 * s2;                                            \
            E[2*h] = e2.x; E[2*h+1] = e2.y;                                       \
        }                                                                         \
        int _tn = (t) + 4; _tn = (_tn < SS) ? _tn : (SS - 1);                     \
        LOADP4(PC, _tn);                                                          \
    } while (0)

        for (int t0 = 1; t0 <= SS; t0 += 4) {
            STEP(r0, t0);
            STEP(r1, t0 + 1);
            STEP(r2, t0 + 2);
            STEP(r3, t0 + 3);
        }
#undef STEP
#undef LOADP4

        norm_e = (__builtin_amdgcn_logf(ncap) - (float)lcap) * (1.0f / L2E);
    } else {
        // wave 1: gold scores, 4 lanes per batch
        const int lb2 = lane >> 2;
        const int ph  = lane & 3;
        const int bb  = g * 16 + lb2;
        const int len = lens[bb];
        const size_t base = (size_t)bb * SS;
        float un2 = 0.f, bi = 0.f;
        for (int t = ph; t < len; t += 4) {
            int lab = labels[base + t];
            un2 += __builtin_amdgcn_logf(PE[(base + t) * 64 + lab]); // log2
            int prev = (t == 0) ? LBL : labels[base + t - 1];
            bi += T[lab * NL + prev];
        }
        float gsum = un2 * (1.0f / L2E) + bi;
        gsum += __shfl_xor(gsum, 1, 64);
        gsum += __shfl_xor(gsum, 2, 64);
        if (ph == 0) {
            gsum += T[(NL - 1) * NL + labels[base + len - 1]];
            gold_sh[lb2] = gsum;
        }
    }

    __syncthreads();
    if (wv == 0 && q == 2) { // lanes 32..47 hold the END-row norm
        float v = norm_e - gold_sh[b];
        v += __shfl_xor(v, 1, 64);
        v += __shfl_xor(v, 2, 64);
        v += __shfl_xor(v, 4, 64);
        v += __shfl_xor(v, 8, 64);
        if (b == 0) atomicAdd(out, v);
    }
}

// ---------------------------------------------------------------------------
extern "C" void kernel_launch(void* const* d_in, const int* in_sizes, int n_in,
                              void* d_out, int out_size, void* d_ws, size_t ws_size,
                              hipStream_t stream) {
    const float* A      = (const float*)d_in[0]; // inputs [128,512,1024]
    const float* W      = (const float*)d_in[1]; // [50,1024]
    const float* bias   = (const float*)d_in[2]; // [50]
    const float* T      = (const float*)d_in[3]; // [52,52]
    const int*   lens   = (const int*)d_in[4];   // [128]
    const int*   labels = (const int*)d_in[5];   // [128,512]
    float* out = (float*)d_out;

    float* PEp = (float*)d_ws;                               // 65536*64*4 = 16.78 MB
    unsigned short* Wbf = (unsigned short*)((char*)d_ws + (size_t)65536 * 64 * 4); // 131 KB

    hipMemsetAsync(d_out, 0, sizeof(float), stream);
    wconv<<<dim3(256), dim3(256), 0, stream>>>(W, Wbf);
    gemm_pe<<<dim3((BB * SS) / 64), dim3(256), 0, stream>>>(A, Wbf, bias, PEp);
    crf_fwd<<<dim3(8), dim3(128), 0, stream>>>(PEp, T, lens, labels, out);
}